// Round 3
// baseline (3100.452 us; speedup 1.0000x reference)
//
#include <hip/hip_runtime.h>
#include <cstdint>

#define B_SZ  1024
#define S_LEN 200
#define H_DIM 256

typedef short s16x8 __attribute__((ext_vector_type(8)));
typedef float f32x4 __attribute__((ext_vector_type(4)));

__device__ __forceinline__ short f2bf(float f){
  uint32_t u = __float_as_uint(f);
  u += 0x7FFFu + ((u >> 16) & 1u);   // RNE
  return (short)(u >> 16);
}
__device__ __forceinline__ float sigm(float x){
  return __fdividef(1.f, 1.f + __expf(-x));
}
__device__ __forceinline__ float tanh_f(float x){
  return 1.f - __fdividef(2.f, __expf(2.f*x) + 1.f);
}

// ---- prep: fp32 -> bf16 weights, split into x-part (wx) and h-part ------
__global__ __launch_bounds__(256) void prep_kernel(
    const float* __restrict__ Wr, const float* __restrict__ Wz,
    const float* __restrict__ Wn, const float* __restrict__ W1,
    short* __restrict__ wx, short* __restrict__ wrzh,
    short* __restrict__ wnh, short* __restrict__ w1b){
  const int NWX=196608, NRZ=131072, NN=65536;
  int i = blockIdx.x*256 + threadIdx.x;
  if(i < NWX){
    int o=i>>8, k=i&255;
    float v = (o<256)? Wr[o*512+k] : (o<512)? Wz[(o-256)*512+k] : Wn[(o-512)*512+k];
    wx[i]=f2bf(v);
  } else if(i < NWX+NRZ){
    int j=i-NWX; int o=j>>8, k=j&255;
    float v=(o<256)? Wr[o*512+256+k] : Wz[(o-256)*512+256+k];
    wrzh[j]=f2bf(v);
  } else if(i < NWX+NRZ+NN){
    int j=i-NWX-NRZ; int o=j>>8, k=j&255;
    wnh[j]=f2bf(Wn[o*512+256+k]);
  } else {
    int j=i-NWX-NRZ-NN;
    w1b[j]=f2bf(W1[j]);
  }
}

// ---- attention scores: relu(combined @ W1^T + b1) @ W2 ------------------
__global__ __launch_bounds__(256) void scores_kernel(
    const float* __restrict__ hs, const float* __restrict__ tgt,
    const short* __restrict__ w1, const float* __restrict__ b1,
    const float* __restrict__ w2, float* __restrict__ scores){
  const int tid = threadIdx.x;
  const int lane = tid & 63;
  const int wv  = tid >> 6;
  const int l15 = lane & 15;
  const int q   = lane >> 4;
  const int gw  = blockIdx.x * 4 + wv;    // 0..3199
  float b1v[8], w2v[8];
  #pragma unroll
  for(int nt=0;nt<8;nt++){ b1v[nt]=b1[nt*16+l15]; w2v[nt]=w2[nt*16+l15]; }
  const short* w1p = w1 + (size_t)l15*512 + q*8;
  for(int it=0; it<2; it++){
    int mt0 = gw + it*3200;               // 0..6399
    int mt1 = mt0 + 6400;                 // 6400..12799
    int m0  = mt0*16 + l15;
    int m1  = mt1*16 + l15;
    int bA  = m0 / S_LEN, sA = m0 - bA*S_LEN;
    int bB  = m1 / S_LEN, sB = m1 - bB*S_LEN;
    const float* arowA = hs  + ((size_t)bA*S_LEN + sA)*H_DIM;
    const float* trowA = tgt + (size_t)bA*H_DIM;
    const float* arowB = hs  + ((size_t)bB*S_LEN + sB)*H_DIM;
    const float* trowB = tgt + (size_t)bB*H_DIM;
    f32x4 acc[2][8];
    #pragma unroll
    for(int u=0;u<2;u++)
      #pragma unroll
      for(int nt=0;nt<8;nt++) acc[u][nt] = (f32x4){0.f,0.f,0.f,0.f};
    for(int kt=0;kt<16;kt++){
      int k0 = kt*32 + q*8;
      const float* srcA = (k0 < H_DIM) ? (arowA + k0) : (trowA + (k0 - H_DIM));
      const float* srcB = (k0 < H_DIM) ? (arowB + k0) : (trowB + (k0 - H_DIM));
      float4 a0 = *(const float4*)(srcA);
      float4 a1 = *(const float4*)(srcA+4);
      float4 c0 = *(const float4*)(srcB);
      float4 c1 = *(const float4*)(srcB+4);
      s16x8 aA, aB;
      aA[0]=f2bf(a0.x); aA[1]=f2bf(a0.y); aA[2]=f2bf(a0.z); aA[3]=f2bf(a0.w);
      aA[4]=f2bf(a1.x); aA[5]=f2bf(a1.y); aA[6]=f2bf(a1.z); aA[7]=f2bf(a1.w);
      aB[0]=f2bf(c0.x); aB[1]=f2bf(c0.y); aB[2]=f2bf(c0.z); aB[3]=f2bf(c0.w);
      aB[4]=f2bf(c1.x); aB[5]=f2bf(c1.y); aB[6]=f2bf(c1.z); aB[7]=f2bf(c1.w);
      #pragma unroll
      for(int nt=0;nt<8;nt++){
        s16x8 bf = *(const s16x8*)(w1p + (size_t)nt*16*512 + kt*32);
        acc[0][nt] = __builtin_amdgcn_mfma_f32_16x16x32_bf16(aA, bf, acc[0][nt], 0, 0, 0);
        acc[1][nt] = __builtin_amdgcn_mfma_f32_16x16x32_bf16(aB, bf, acc[1][nt], 0, 0, 0);
      }
    }
    #pragma unroll
    for(int u=0;u<2;u++){
      float sr0=0.f, sr1=0.f, sr2=0.f, sr3=0.f;
      #pragma unroll
      for(int nt=0;nt<8;nt++){
        f32x4 h4 = acc[u][nt];
        sr0 += fmaxf(h4[0]+b1v[nt],0.f)*w2v[nt];
        sr1 += fmaxf(h4[1]+b1v[nt],0.f)*w2v[nt];
        sr2 += fmaxf(h4[2]+b1v[nt],0.f)*w2v[nt];
        sr3 += fmaxf(h4[3]+b1v[nt],0.f)*w2v[nt];
      }
      #pragma unroll
      for(int mask=1; mask<16; mask<<=1){
        sr0 += __shfl_xor(sr0, mask, 64);
        sr1 += __shfl_xor(sr1, mask, 64);
        sr2 += __shfl_xor(sr2, mask, 64);
        sr3 += __shfl_xor(sr3, mask, 64);
      }
      if(l15 < 4){
        float outv = (l15==0)?sr0:(l15==1)?sr1:(l15==2)?sr2:sr3;
        int mt = (u==0)?mt0:mt1;
        scores[(size_t)mt*16 + q*4 + l15] = outv;
      }
    }
  }
}

// ---- masked softmax over S per batch row --------------------------------
__global__ __launch_bounds__(256) void softmax_kernel(
    const float* __restrict__ scores, const int* __restrict__ lengths,
    float* __restrict__ att){
  const int b = blockIdx.x;
  const int s = threadIdx.x;
  const int lane = s & 63, wv = s >> 6;
  __shared__ float red[4];
  __shared__ float red2[4];
  float sc = -1e9f;
  if(s < S_LEN){
    float v = scores[(size_t)b*S_LEN + s];
    sc = (s < lengths[b]) ? v : -1e9f;
  }
  float mx = (s < S_LEN) ? sc : -INFINITY;
  #pragma unroll
  for(int mask=1; mask<64; mask<<=1) mx = fmaxf(mx, __shfl_xor(mx, mask, 64));
  if(lane==0) red[wv] = mx;
  __syncthreads();
  mx = fmaxf(fmaxf(red[0],red[1]), fmaxf(red[2],red[3]));
  float e = (s < S_LEN) ? expf(sc - mx) : 0.f;
  float sum = e;
  #pragma unroll
  for(int mask=1; mask<64; mask<<=1) sum += __shfl_xor(sum, mask, 64);
  if(lane==0) red2[wv] = sum;
  __syncthreads();
  sum = red2[0]+red2[1]+red2[2]+red2[3];
  if(s < S_LEN) att[(size_t)b*S_LEN + s] = e / sum;
}

// ---- GRU scan: h-weights register-resident, x-proj chunked (CH=4) -------
// 64 blocks x 16 batch rows x 512 threads (8 waves).
// __launch_bounds__(512, 2): min 2 waves/EU -> 256 VGPR cap. The 192
// register-resident weight frags MUST NOT spill (R2: 128-cap spilled them
// -> 955 MB scratch traffic, 2715 us).
__global__ __launch_bounds__(512, 2) void scan_kernel(
    const float* __restrict__ hs, const float* __restrict__ att,
    const short* __restrict__ wx, const short* __restrict__ wrzh,
    const short* __restrict__ wnh,
    const float* __restrict__ br, const float* __restrict__ bz,
    const float* __restrict__ bn, float* __restrict__ out){
  // LDS layout (bytes):
  //   [0,98304)        XP   fp16 [4][16][768]  x-projections (+bias) for chunk
  //   [98304,114688)   hO   f32  [16][256]     master h
  //   [114688,148480)  union: xstage bf16 [64][264] (chunk GEMM A)
  //                        | comb bf16 [16][264] + zS fp16 [16][256]
  //   [148480,148736)  attc f32 [4][16]
  __shared__ __align__(16) char smem[148736];
  _Float16* XP   = (_Float16*)smem;
  float*    hO   = (float*)(smem + 98304);
  short*    xst  = (short*)(smem + 114688);
  short*    comb = (short*)(smem + 114688);
  _Float16* zS   = (_Float16*)(smem + 123136);
  float*    attc = (float*)(smem + 148480);

  const int tid = threadIdx.x;
  const int lane = tid & 63;
  const int wv  = tid >> 6;         // 0..7
  const int l15 = lane & 15;
  const int q   = lane >> 4;
  const int b0  = blockIdx.x * 16;

  // register-resident h-part weight fragments (192 VGPRs)
  s16x8 wfr[32], wfn[16];
  #pragma unroll
  for(int kt=0;kt<8;kt++)
    #pragma unroll
    for(int i=0;i<4;i++)
      wfr[kt*4+i] = *(const s16x8*)(wrzh + (size_t)((wv*4+i)*16+l15)*256 + kt*32 + q*8);
  #pragma unroll
  for(int kt=0;kt<8;kt++)
    #pragma unroll
    for(int i=0;i<2;i++)
      wfn[kt*2+i] = *(const s16x8*)(wnh + (size_t)((wv*2+i)*16+l15)*256 + kt*32 + q*8);
  float biasv[6];
  #pragma unroll
  for(int j=0;j<6;j++){
    int o=(wv*6+j)*16+l15;
    biasv[j] = (o<256)? br[o] : (o<512)? bz[o-256] : bn[o-512];
  }
  for(int i=tid;i<4096;i+=512) hO[i]=0.f;

  for(int c=0;c<50;c++){
    const int t0=c*4;
    __syncthreads();                         // B1: prior step writes done; xst region free
    // stage x (4 steps x 16 rows) as bf16 into xstage
    #pragma unroll
    for(int jj=0;jj<4;jj++){
      int idx = tid + jj*512;                // 0..2047
      int r = idx>>5, k=(idx&31)*8;          // r = tl*16+bl
      int bl=r&15, tl=r>>4;
      const float* src = hs + ((size_t)(b0+bl)*S_LEN + (t0+tl))*H_DIM + k;
      float4 v0=*(const float4*)src, v1=*(const float4*)(src+4);
      s16x8 xv;
      xv[0]=f2bf(v0.x); xv[1]=f2bf(v0.y); xv[2]=f2bf(v0.z); xv[3]=f2bf(v0.w);
      xv[4]=f2bf(v1.x); xv[5]=f2bf(v1.y); xv[6]=f2bf(v1.z); xv[7]=f2bf(v1.w);
      *(s16x8*)(xst + r*264 + k) = xv;
    }
    if(tid<64) attc[tid] = att[(size_t)(b0+(tid&15))*S_LEN + t0 + (tid>>4)];
    __syncthreads();                         // B2: xstage + attc ready
    // chunk GEMM: XP[tl][row][0:768] = x @ Wx^T + bias
    // 6 passes x 1 n-tile: only 16 live acc regs (keep pressure < 256)
    #pragma unroll
    for(int p=0;p<6;p++){
      f32x4 xacc[4];
      #pragma unroll
      for(int tl=0;tl<4;tl++) xacc[tl]=(f32x4){0.f,0.f,0.f,0.f};
      #pragma unroll
      for(int kt=0;kt<8;kt++){
        s16x8 bf0 = *(const s16x8*)(wx + (size_t)((wv*6+p)*16+l15)*256 + kt*32+q*8);
        #pragma unroll
        for(int tl=0;tl<4;tl++){
          s16x8 a = *(const s16x8*)(xst + (tl*16+l15)*264 + kt*32 + q*8);
          xacc[tl]=__builtin_amdgcn_mfma_f32_16x16x32_bf16(a,bf0,xacc[tl],0,0,0);
        }
      }
      int col=(wv*6+p)*16+l15;
      float bias=biasv[p];
      #pragma unroll
      for(int tl=0;tl<4;tl++)
        #pragma unroll
        for(int reg=0;reg<4;reg++)
          XP[(size_t)(tl*16 + q*4+reg)*768 + col] = (_Float16)(xacc[tl][reg] + bias);
    }
    __syncthreads();                         // B3: XP ready; xstage reads done
    // rebuild comb (=h bf16) from hO over the aliased region
    #pragma unroll
    for(int jj=0;jj<8;jj++){
      int idx=tid+jj*512;                    // 0..4095
      int rr=idx>>8, cc=idx&255;
      comb[rr*264+cc]=f2bf(hO[idx]);
    }
    // ---- 4 recurrence steps ----
    for(int tl=0;tl<4;tl++){
      __syncthreads();                       // A: comb(h) ready
      f32x4 acc[4];
      #pragma unroll
      for(int i=0;i<4;i++) acc[i]=(f32x4){0.f,0.f,0.f,0.f};
      #pragma unroll
      for(int kt=0;kt<8;kt++){
        s16x8 a = *(const s16x8*)(comb + l15*264 + kt*32+q*8);
        #pragma unroll
        for(int i=0;i<4;i++)
          acc[i]=__builtin_amdgcn_mfma_f32_16x16x32_bf16(a,wfr[kt*4+i],acc[i],0,0,0);
      }
      __syncthreads();                       // B: GEMM1 comb reads done
      #pragma unroll
      for(int i=0;i<4;i++){
        int o=(wv*4+i)*16+l15;               // 0..511, wave-uniform branch below
        #pragma unroll
        for(int reg=0;reg<4;reg++){
          int row=q*4+reg;
          float pre = acc[i][reg] + (float)XP[(size_t)(tl*16+row)*768 + o];
          float g = sigm(pre);
          if(o<256){
            comb[row*264+o] = f2bf(g*hO[row*256+o]);      // r*h
          } else {
            zS[row*256+(o-256)] = (_Float16)(g*attc[tl*16+row]); // z = sig*att
          }
        }
      }
      __syncthreads();                       // C: r*h / z written
      f32x4 acc2[2];
      #pragma unroll
      for(int i=0;i<2;i++) acc2[i]=(f32x4){0.f,0.f,0.f,0.f};
      #pragma unroll
      for(int kt=0;kt<8;kt++){
        s16x8 a = *(const s16x8*)(comb + l15*264 + kt*32+q*8);
        #pragma unroll
        for(int i=0;i<2;i++)
          acc2[i]=__builtin_amdgcn_mfma_f32_16x16x32_bf16(a,wfn[kt*2+i],acc2[i],0,0,0);
      }
      __syncthreads();                       // D: GEMM2 comb reads done
      #pragma unroll
      for(int i=0;i<2;i++){
        int cc=(wv*2+i)*16+l15;
        #pragma unroll
        for(int reg=0;reg<4;reg++){
          int row=q*4+reg;
          float nv = tanh_f(acc2[i][reg] + (float)XP[(size_t)(tl*16+row)*768 + 512+cc]);
          float z  = (float)zS[row*256+cc];
          float hp = hO[row*256+cc];
          float hn = fmaf(z, nv-hp, hp);
          hO[row*256+cc]=hn;
          comb[row*264+cc]=f2bf(hn);
        }
      }
    }
  }
  __syncthreads();
  float4 o0 = *(float4*)(hO + tid*8);
  float4 o1 = *(float4*)(hO + tid*8 + 4);
  float* op = out + (size_t)b0*H_DIM + tid*8;
  *(float4*)op = o0; *(float4*)(op+4)=o1;
}

extern "C" void kernel_launch(void* const* d_in, const int* in_sizes, int n_in,
                              void* d_out, int out_size, void* d_ws, size_t ws_size,
                              hipStream_t stream) {
  const float* hs  = (const float*)d_in[0];
  const float* tgt = (const float*)d_in[1];
  const int*   len = (const int*)d_in[2];
  const float* W1  = (const float*)d_in[3];
  const float* b1  = (const float*)d_in[4];
  const float* W2  = (const float*)d_in[5];
  const float* Wr  = (const float*)d_in[6];
  const float* br  = (const float*)d_in[7];
  const float* Wz  = (const float*)d_in[8];
  const float* bz  = (const float*)d_in[9];
  const float* Wn  = (const float*)d_in[10];
  const float* bn  = (const float*)d_in[11];
  float* out = (float*)d_out;
  // ws: wx[768*256] | wrzh[512*256] | wnh[256*256] | w1b[128*512] | scores | att
  short* wx   = (short*)d_ws;
  short* wrzh = wx + 196608;
  short* wnh  = wrzh + 131072;
  short* w1b  = wnh + 65536;
  float* scores = (float*)(w1b + 65536);
  float* att    = scores + (size_t)B_SZ*S_LEN;
  prep_kernel<<<1792, 256, 0, stream>>>(Wr, Wz, Wn, W1, wx, wrzh, wnh, w1b);
  scores_kernel<<<800, 256, 0, stream>>>(hs, tgt, w1b, b1, W2, scores);
  softmax_kernel<<<1024, 256, 0, stream>>>(scores, len, att);
  scan_kernel<<<64, 512, 0, stream>>>(hs, att, wx, wrzh, wnh, br, bz, bn, out);
}

// Round 4
// 3067.258 us; speedup vs baseline: 1.0108x; 1.0108x over previous
//
#include <hip/hip_runtime.h>
#include <cstdint>

#define B_SZ  1024
#define S_LEN 200
#define H_DIM 256

typedef short s16x8 __attribute__((ext_vector_type(8)));
typedef float f32x4 __attribute__((ext_vector_type(4)));

__device__ __forceinline__ short f2bf(float f){
  uint32_t u = __float_as_uint(f);
  u += 0x7FFFu + ((u >> 16) & 1u);   // RNE
  return (short)(u >> 16);
}
__device__ __forceinline__ float sigm(float x){
  return __fdividef(1.f, 1.f + __expf(-x));
}
__device__ __forceinline__ float tanh_f(float x){
  return 1.f - __fdividef(2.f, __expf(2.f*x) + 1.f);
}

// ---- prep: fp32 -> bf16 weights, split into x-part (wx) and h-part ------
__global__ __launch_bounds__(256) void prep_kernel(
    const float* __restrict__ Wr, const float* __restrict__ Wz,
    const float* __restrict__ Wn, const float* __restrict__ W1,
    short* __restrict__ wx, short* __restrict__ wrzh,
    short* __restrict__ wnh, short* __restrict__ w1b){
  const int NWX=196608, NRZ=131072, NN=65536;
  int i = blockIdx.x*256 + threadIdx.x;
  if(i < NWX){
    int o=i>>8, k=i&255;
    float v = (o<256)? Wr[o*512+k] : (o<512)? Wz[(o-256)*512+k] : Wn[(o-512)*512+k];
    wx[i]=f2bf(v);
  } else if(i < NWX+NRZ){
    int j=i-NWX; int o=j>>8, k=j&255;
    float v=(o<256)? Wr[o*512+256+k] : Wz[(o-256)*512+256+k];
    wrzh[j]=f2bf(v);
  } else if(i < NWX+NRZ+NN){
    int j=i-NWX-NRZ; int o=j>>8, k=j&255;
    wnh[j]=f2bf(Wn[o*512+256+k]);
  } else {
    int j=i-NWX-NRZ-NN;
    w1b[j]=f2bf(W1[j]);
  }
}

// ---- attention scores: relu(combined @ W1^T + b1) @ W2 ------------------
__global__ __launch_bounds__(256) void scores_kernel(
    const float* __restrict__ hs, const float* __restrict__ tgt,
    const short* __restrict__ w1, const float* __restrict__ b1,
    const float* __restrict__ w2, float* __restrict__ scores){
  const int tid = threadIdx.x;
  const int lane = tid & 63;
  const int wv  = tid >> 6;
  const int l15 = lane & 15;
  const int q   = lane >> 4;
  const int gw  = blockIdx.x * 4 + wv;    // 0..3199
  float b1v[8], w2v[8];
  #pragma unroll
  for(int nt=0;nt<8;nt++){ b1v[nt]=b1[nt*16+l15]; w2v[nt]=w2[nt*16+l15]; }
  const short* w1p = w1 + (size_t)l15*512 + q*8;
  for(int it=0; it<2; it++){
    int mt0 = gw + it*3200;               // 0..6399
    int mt1 = mt0 + 6400;                 // 6400..12799
    int m0  = mt0*16 + l15;
    int m1  = mt1*16 + l15;
    int bA  = m0 / S_LEN, sA = m0 - bA*S_LEN;
    int bB  = m1 / S_LEN, sB = m1 - bB*S_LEN;
    const float* arowA = hs  + ((size_t)bA*S_LEN + sA)*H_DIM;
    const float* trowA = tgt + (size_t)bA*H_DIM;
    const float* arowB = hs  + ((size_t)bB*S_LEN + sB)*H_DIM;
    const float* trowB = tgt + (size_t)bB*H_DIM;
    f32x4 acc[2][8];
    #pragma unroll
    for(int u=0;u<2;u++)
      #pragma unroll
      for(int nt=0;nt<8;nt++) acc[u][nt] = (f32x4){0.f,0.f,0.f,0.f};
    for(int kt=0;kt<16;kt++){
      int k0 = kt*32 + q*8;
      const float* srcA = (k0 < H_DIM) ? (arowA + k0) : (trowA + (k0 - H_DIM));
      const float* srcB = (k0 < H_DIM) ? (arowB + k0) : (trowB + (k0 - H_DIM));
      float4 a0 = *(const float4*)(srcA);
      float4 a1 = *(const float4*)(srcA+4);
      float4 c0 = *(const float4*)(srcB);
      float4 c1 = *(const float4*)(srcB+4);
      s16x8 aA, aB;
      aA[0]=f2bf(a0.x); aA[1]=f2bf(a0.y); aA[2]=f2bf(a0.z); aA[3]=f2bf(a0.w);
      aA[4]=f2bf(a1.x); aA[5]=f2bf(a1.y); aA[6]=f2bf(a1.z); aA[7]=f2bf(a1.w);
      aB[0]=f2bf(c0.x); aB[1]=f2bf(c0.y); aB[2]=f2bf(c0.z); aB[3]=f2bf(c0.w);
      aB[4]=f2bf(c1.x); aB[5]=f2bf(c1.y); aB[6]=f2bf(c1.z); aB[7]=f2bf(c1.w);
      #pragma unroll
      for(int nt=0;nt<8;nt++){
        s16x8 bf = *(const s16x8*)(w1p + (size_t)nt*16*512 + kt*32);
        acc[0][nt] = __builtin_amdgcn_mfma_f32_16x16x32_bf16(aA, bf, acc[0][nt], 0, 0, 0);
        acc[1][nt] = __builtin_amdgcn_mfma_f32_16x16x32_bf16(aB, bf, acc[1][nt], 0, 0, 0);
      }
    }
    #pragma unroll
    for(int u=0;u<2;u++){
      float sr0=0.f, sr1=0.f, sr2=0.f, sr3=0.f;
      #pragma unroll
      for(int nt=0;nt<8;nt++){
        f32x4 h4 = acc[u][nt];
        sr0 += fmaxf(h4[0]+b1v[nt],0.f)*w2v[nt];
        sr1 += fmaxf(h4[1]+b1v[nt],0.f)*w2v[nt];
        sr2 += fmaxf(h4[2]+b1v[nt],0.f)*w2v[nt];
        sr3 += fmaxf(h4[3]+b1v[nt],0.f)*w2v[nt];
      }
      #pragma unroll
      for(int mask=1; mask<16; mask<<=1){
        sr0 += __shfl_xor(sr0, mask, 64);
        sr1 += __shfl_xor(sr1, mask, 64);
        sr2 += __shfl_xor(sr2, mask, 64);
        sr3 += __shfl_xor(sr3, mask, 64);
      }
      if(l15 < 4){
        float outv = (l15==0)?sr0:(l15==1)?sr1:(l15==2)?sr2:sr3;
        int mt = (u==0)?mt0:mt1;
        scores[(size_t)mt*16 + q*4 + l15] = outv;
      }
    }
  }
}

// ---- masked softmax over S per batch row --------------------------------
__global__ __launch_bounds__(256) void softmax_kernel(
    const float* __restrict__ scores, const int* __restrict__ lengths,
    float* __restrict__ att){
  const int b = blockIdx.x;
  const int s = threadIdx.x;
  const int lane = s & 63, wv = s >> 6;
  __shared__ float red[4];
  __shared__ float red2[4];
  float sc = -1e9f;
  if(s < S_LEN){
    float v = scores[(size_t)b*S_LEN + s];
    sc = (s < lengths[b]) ? v : -1e9f;
  }
  float mx = (s < S_LEN) ? sc : -INFINITY;
  #pragma unroll
  for(int mask=1; mask<64; mask<<=1) mx = fmaxf(mx, __shfl_xor(mx, mask, 64));
  if(lane==0) red[wv] = mx;
  __syncthreads();
  mx = fmaxf(fmaxf(red[0],red[1]), fmaxf(red[2],red[3]));
  float e = (s < S_LEN) ? expf(sc - mx) : 0.f;
  float sum = e;
  #pragma unroll
  for(int mask=1; mask<64; mask<<=1) sum += __shfl_xor(sum, mask, 64);
  if(lane==0) red2[wv] = sum;
  __syncthreads();
  sum = red2[0]+red2[1]+red2[2]+red2[3];
  if(s < S_LEN) att[(size_t)b*S_LEN + s] = e / sum;
}

// ---- GRU scan: h-weights register-resident, x-proj chunked (CH=4) -------
// 64 blocks x 16 batch rows x 512 threads (8 waves = 2 waves/EU).
// amdgpu_waves_per_eu(2,2) => VGPR budget 256/wave (512-reg pool / 2).
// R2/R3 post-mortem: __launch_bounds__(512,{-,2}) produced a 128-reg cap
// (second arg treated as blocks/CU) and spilled the 192 resident weight
// frags -> 760-955 MB scratch HBM traffic. The explicit backend attribute
// is unambiguous.
__global__ __attribute__((amdgpu_flat_work_group_size(512,512), amdgpu_waves_per_eu(2,2)))
void scan_kernel(
    const float* __restrict__ hs, const float* __restrict__ att,
    const short* __restrict__ wx, const short* __restrict__ wrzh,
    const short* __restrict__ wnh,
    const float* __restrict__ br, const float* __restrict__ bz,
    const float* __restrict__ bn, float* __restrict__ out){
  // LDS layout (bytes):
  //   [0,99328)         XP    fp16 [4][16][776] x-projections (+bias), pad 768->776
  //   [99328,115968)    hO    f32  [16][260]    master h, pad 256->260
  //   [115968,149760)   union: xstage bf16 [64][264] (chunk GEMM A)
  //                         | comb0 bf16 [16][264] (h)       @ +0
  //                         | comb1 bf16 [16][264] (r*h)     @ +8448
  //                         | zS    fp16 [16][264]           @ +16896
  //   [149760,150016)   attc  f32 [4][16]
  __shared__ __align__(16) char smem[150016];
  _Float16* XP    = (_Float16*)smem;
  float*    hO    = (float*)(smem + 99328);
  short*    xst   = (short*)(smem + 115968);
  short*    comb0 = (short*)(smem + 115968);
  short*    comb1 = (short*)(smem + 115968 + 8448);
  _Float16* zS    = (_Float16*)(smem + 115968 + 16896);
  float*    attc  = (float*)(smem + 149760);

  const int tid = threadIdx.x;
  const int lane = tid & 63;
  const int wv  = tid >> 6;         // 0..7
  const int l15 = lane & 15;
  const int q   = lane >> 4;
  const int b0  = blockIdx.x * 16;

  // register-resident h-part weight fragments (192 VGPRs)
  s16x8 wfr[32], wfn[16];
  #pragma unroll
  for(int kt=0;kt<8;kt++)
    #pragma unroll
    for(int i=0;i<4;i++)
      wfr[kt*4+i] = *(const s16x8*)(wrzh + (size_t)((wv*4+i)*16+l15)*256 + kt*32 + q*8);
  #pragma unroll
  for(int kt=0;kt<8;kt++)
    #pragma unroll
    for(int i=0;i<2;i++)
      wfn[kt*2+i] = *(const s16x8*)(wnh + (size_t)((wv*2+i)*16+l15)*256 + kt*32 + q*8);
  float biasv[6];
  #pragma unroll
  for(int j=0;j<6;j++){
    int o=(wv*6+j)*16+l15;
    biasv[j] = (o<256)? br[o] : (o<512)? bz[o-256] : bn[o-512];
  }
  for(int i=tid;i<16*260;i+=512) hO[i]=0.f;

  for(int c=0;c<50;c++){
    const int t0=c*4;
    __syncthreads();                         // B1: prior step reads/writes done; U free
    // stage x (4 steps x 16 rows) as bf16 into xstage
    #pragma unroll
    for(int jj=0;jj<4;jj++){
      int idx = tid + jj*512;                // 0..2047
      int r = idx>>5, k=(idx&31)*8;          // r = tl*16+bl
      int bl=r&15, tl=r>>4;
      const float* src = hs + ((size_t)(b0+bl)*S_LEN + (t0+tl))*H_DIM + k;
      float4 v0=*(const float4*)src, v1=*(const float4*)(src+4);
      s16x8 xv;
      xv[0]=f2bf(v0.x); xv[1]=f2bf(v0.y); xv[2]=f2bf(v0.z); xv[3]=f2bf(v0.w);
      xv[4]=f2bf(v1.x); xv[5]=f2bf(v1.y); xv[6]=f2bf(v1.z); xv[7]=f2bf(v1.w);
      *(s16x8*)(xst + r*264 + k) = xv;
    }
    if(tid<64) attc[tid] = att[(size_t)(b0+(tid&15))*S_LEN + t0 + (tid>>4)];
    __syncthreads();                         // B2: xstage + attc ready
    // chunk GEMM: XP[tl][row][0:768] = x @ Wx^T + bias
    // 6 passes x 1 n-tile: 16 live acc regs (keep pressure < 256)
    #pragma unroll
    for(int p=0;p<6;p++){
      f32x4 xacc[4];
      #pragma unroll
      for(int tl=0;tl<4;tl++) xacc[tl]=(f32x4){0.f,0.f,0.f,0.f};
      #pragma unroll
      for(int kt=0;kt<8;kt++){
        s16x8 bf0 = *(const s16x8*)(wx + (size_t)((wv*6+p)*16+l15)*256 + kt*32+q*8);
        #pragma unroll
        for(int tl=0;tl<4;tl++){
          s16x8 a = *(const s16x8*)(xst + (tl*16+l15)*264 + kt*32 + q*8);
          xacc[tl]=__builtin_amdgcn_mfma_f32_16x16x32_bf16(a,bf0,xacc[tl],0,0,0);
        }
      }
      int col=(wv*6+p)*16+l15;
      float bias=biasv[p];
      #pragma unroll
      for(int tl=0;tl<4;tl++)
        #pragma unroll
        for(int reg=0;reg<4;reg++)
          XP[(size_t)(tl*16 + q*4+reg)*776 + col] = (_Float16)(xacc[tl][reg] + bias);
    }
    __syncthreads();                         // B3: XP ready; xstage reads done
    // rebuild comb0 (=h bf16) from hO over the aliased region
    #pragma unroll
    for(int jj=0;jj<8;jj++){
      int idx=tid+jj*512;                    // 0..4095
      int rr=idx>>8, cc=idx&255;
      comb0[rr*264+cc]=f2bf(hO[rr*260+cc]);
    }
    __syncthreads();                         // B4: comb0 ready
    // ---- 4 recurrence steps, 2 barriers each (comb double-buffered) ----
    for(int tl=0;tl<4;tl++){
      // GEMM1: h(16x256) @ [Wr_h;Wz_h]^T ; reads comb0
      f32x4 acc[4];
      #pragma unroll
      for(int i=0;i<4;i++) acc[i]=(f32x4){0.f,0.f,0.f,0.f};
      #pragma unroll
      for(int kt=0;kt<8;kt++){
        s16x8 a = *(const s16x8*)(comb0 + l15*264 + kt*32+q*8);
        #pragma unroll
        for(int i=0;i<4;i++)
          acc[i]=__builtin_amdgcn_mfma_f32_16x16x32_bf16(a,wfr[kt*4+i],acc[i],0,0,0);
      }
      // epi1: r -> comb1 (waves 0-3), z -> zS (waves 4-7); no comb0 writes
      #pragma unroll
      for(int i=0;i<4;i++){
        int o=(wv*4+i)*16+l15;               // wave-uniform branch below
        #pragma unroll
        for(int reg=0;reg<4;reg++){
          int row=q*4+reg;
          float pre = acc[i][reg] + (float)XP[(size_t)(tl*16+row)*776 + o];
          float g = sigm(pre);
          if(o<256){
            comb1[row*264+o] = f2bf(g*hO[row*260+o]);          // r*h
          } else {
            zS[row*264+(o-256)] = (_Float16)(g*attc[tl*16+row]); // z = sig*att
          }
        }
      }
      __syncthreads();                       // C: comb1/zS ready, comb0 reads done
      // GEMM2: [r*h](16x256) @ Wn_h^T ; reads comb1
      f32x4 acc2[2];
      #pragma unroll
      for(int i=0;i<2;i++) acc2[i]=(f32x4){0.f,0.f,0.f,0.f};
      #pragma unroll
      for(int kt=0;kt<8;kt++){
        s16x8 a = *(const s16x8*)(comb1 + l15*264 + kt*32+q*8);
        #pragma unroll
        for(int i=0;i<2;i++)
          acc2[i]=__builtin_amdgcn_mfma_f32_16x16x32_bf16(a,wfn[kt*2+i],acc2[i],0,0,0);
      }
      // epi2: h update -> hO + comb0 (next step's GEMM1 input)
      #pragma unroll
      for(int i=0;i<2;i++){
        int cc=(wv*2+i)*16+l15;
        #pragma unroll
        for(int reg=0;reg<4;reg++){
          int row=q*4+reg;
          float nv = tanh_f(acc2[i][reg] + (float)XP[(size_t)(tl*16+row)*776 + 512+cc]);
          float z  = (float)zS[row*264+cc];
          float hp = hO[row*260+cc];
          float hn = fmaf(z, nv-hp, hp);
          hO[row*260+cc]=hn;
          comb0[row*264+cc]=f2bf(hn);
        }
      }
      __syncthreads();                       // A: comb0(next h) ready, comb1 reads done
    }
  }
  float4 o0, o1;
  const int orow = tid>>5, ocol = (tid&31)*8;
  o0.x=hO[orow*260+ocol+0]; o0.y=hO[orow*260+ocol+1];
  o0.z=hO[orow*260+ocol+2]; o0.w=hO[orow*260+ocol+3];
  o1.x=hO[orow*260+ocol+4]; o1.y=hO[orow*260+ocol+5];
  o1.z=hO[orow*260+ocol+6]; o1.w=hO[orow*260+ocol+7];
  float* op = out + (size_t)(b0+orow)*H_DIM + ocol;
  *(float4*)op = o0; *(float4*)(op+4)=o1;
}

extern "C" void kernel_launch(void* const* d_in, const int* in_sizes, int n_in,
                              void* d_out, int out_size, void* d_ws, size_t ws_size,
                              hipStream_t stream) {
  const float* hs  = (const float*)d_in[0];
  const float* tgt = (const float*)d_in[1];
  const int*   len = (const int*)d_in[2];
  const float* W1  = (const float*)d_in[3];
  const float* b1  = (const float*)d_in[4];
  const float* W2  = (const float*)d_in[5];
  const float* Wr  = (const float*)d_in[6];
  const float* br  = (const float*)d_in[7];
  const float* Wz  = (const float*)d_in[8];
  const float* bz  = (const float*)d_in[9];
  const float* Wn  = (const float*)d_in[10];
  const float* bn  = (const float*)d_in[11];
  float* out = (float*)d_out;
  // ws: wx[768*256] | wrzh[512*256] | wnh[256*256] | w1b[128*512] | scores | att
  short* wx   = (short*)d_ws;
  short* wrzh = wx + 196608;
  short* wnh  = wrzh + 131072;
  short* w1b  = wnh + 65536;
  float* scores = (float*)(w1b + 65536);
  float* att    = scores + (size_t)B_SZ*S_LEN;
  prep_kernel<<<1792, 256, 0, stream>>>(Wr, Wz, Wn, W1, wx, wrzh, wnh, w1b);
  scores_kernel<<<800, 256, 0, stream>>>(hs, tgt, w1b, b1, W2, scores);
  softmax_kernel<<<1024, 256, 0, stream>>>(scores, len, att);
  scan_kernel<<<64, 512, 0, stream>>>(hs, att, wx, wrzh, wnh, br, bz, bn, out);
}

// Round 5
// 2426.628 us; speedup vs baseline: 1.2777x; 1.2640x over previous
//
#include <hip/hip_runtime.h>
#include <cstdint>

#define B_SZ  1024
#define S_LEN 200
#define H_DIM 256

typedef short s16x8 __attribute__((ext_vector_type(8)));
typedef float f32x4 __attribute__((ext_vector_type(4)));

__device__ __forceinline__ short f2bf(float f){
  uint32_t u = __float_as_uint(f);
  u += 0x7FFFu + ((u >> 16) & 1u);   // RNE
  return (short)(u >> 16);
}
__device__ __forceinline__ float sigm(float x){
  return __fdividef(1.f, 1.f + __expf(-x));
}
__device__ __forceinline__ float tanh_f(float x){
  return 1.f - __fdividef(2.f, __expf(2.f*x) + 1.f);
}

// ---- prep: fp32 -> bf16 weights, split into x-part (wx) and h-part ------
__global__ __launch_bounds__(256) void prep_kernel(
    const float* __restrict__ Wr, const float* __restrict__ Wz,
    const float* __restrict__ Wn, const float* __restrict__ W1,
    short* __restrict__ wx, short* __restrict__ wrzh,
    short* __restrict__ wnh, short* __restrict__ w1b){
  const int NWX=196608, NRZ=131072, NN=65536;
  int i = blockIdx.x*256 + threadIdx.x;
  if(i < NWX){
    int o=i>>8, k=i&255;
    float v = (o<256)? Wr[o*512+k] : (o<512)? Wz[(o-256)*512+k] : Wn[(o-512)*512+k];
    wx[i]=f2bf(v);
  } else if(i < NWX+NRZ){
    int j=i-NWX; int o=j>>8, k=j&255;
    float v=(o<256)? Wr[o*512+256+k] : Wz[(o-256)*512+256+k];
    wrzh[j]=f2bf(v);
  } else if(i < NWX+NRZ+NN){
    int j=i-NWX-NRZ; int o=j>>8, k=j&255;
    wnh[j]=f2bf(Wn[o*512+256+k]);
  } else {
    int j=i-NWX-NRZ-NN;
    w1b[j]=f2bf(W1[j]);
  }
}

// ---- attention scores: relu(combined @ W1^T + b1) @ W2 ------------------
__global__ __launch_bounds__(256) void scores_kernel(
    const float* __restrict__ hs, const float* __restrict__ tgt,
    const short* __restrict__ w1, const float* __restrict__ b1,
    const float* __restrict__ w2, float* __restrict__ scores){
  const int tid = threadIdx.x;
  const int lane = tid & 63;
  const int wv  = tid >> 6;
  const int l15 = lane & 15;
  const int q   = lane >> 4;
  const int gw  = blockIdx.x * 4 + wv;    // 0..3199
  float b1v[8], w2v[8];
  #pragma unroll
  for(int nt=0;nt<8;nt++){ b1v[nt]=b1[nt*16+l15]; w2v[nt]=w2[nt*16+l15]; }
  const short* w1p = w1 + (size_t)l15*512 + q*8;
  for(int it=0; it<2; it++){
    int mt0 = gw + it*3200;               // 0..6399
    int mt1 = mt0 + 6400;                 // 6400..12799
    int m0  = mt0*16 + l15;
    int m1  = mt1*16 + l15;
    int bA  = m0 / S_LEN, sA = m0 - bA*S_LEN;
    int bB  = m1 / S_LEN, sB = m1 - bB*S_LEN;
    const float* arowA = hs  + ((size_t)bA*S_LEN + sA)*H_DIM;
    const float* trowA = tgt + (size_t)bA*H_DIM;
    const float* arowB = hs  + ((size_t)bB*S_LEN + sB)*H_DIM;
    const float* trowB = tgt + (size_t)bB*H_DIM;
    f32x4 acc[2][8];
    #pragma unroll
    for(int u=0;u<2;u++)
      #pragma unroll
      for(int nt=0;nt<8;nt++) acc[u][nt] = (f32x4){0.f,0.f,0.f,0.f};
    for(int kt=0;kt<16;kt++){
      int k0 = kt*32 + q*8;
      const float* srcA = (k0 < H_DIM) ? (arowA + k0) : (trowA + (k0 - H_DIM));
      const float* srcB = (k0 < H_DIM) ? (arowB + k0) : (trowB + (k0 - H_DIM));
      float4 a0 = *(const float4*)(srcA);
      float4 a1 = *(const float4*)(srcA+4);
      float4 c0 = *(const float4*)(srcB);
      float4 c1 = *(const float4*)(srcB+4);
      s16x8 aA, aB;
      aA[0]=f2bf(a0.x); aA[1]=f2bf(a0.y); aA[2]=f2bf(a0.z); aA[3]=f2bf(a0.w);
      aA[4]=f2bf(a1.x); aA[5]=f2bf(a1.y); aA[6]=f2bf(a1.z); aA[7]=f2bf(a1.w);
      aB[0]=f2bf(c0.x); aB[1]=f2bf(c0.y); aB[2]=f2bf(c0.z); aB[3]=f2bf(c0.w);
      aB[4]=f2bf(c1.x); aB[5]=f2bf(c1.y); aB[6]=f2bf(c1.z); aB[7]=f2bf(c1.w);
      #pragma unroll
      for(int nt=0;nt<8;nt++){
        s16x8 bf = *(const s16x8*)(w1p + (size_t)nt*16*512 + kt*32);
        acc[0][nt] = __builtin_amdgcn_mfma_f32_16x16x32_bf16(aA, bf, acc[0][nt], 0, 0, 0);
        acc[1][nt] = __builtin_amdgcn_mfma_f32_16x16x32_bf16(aB, bf, acc[1][nt], 0, 0, 0);
      }
    }
    #pragma unroll
    for(int u=0;u<2;u++){
      float sr0=0.f, sr1=0.f, sr2=0.f, sr3=0.f;
      #pragma unroll
      for(int nt=0;nt<8;nt++){
        f32x4 h4 = acc[u][nt];
        sr0 += fmaxf(h4[0]+b1v[nt],0.f)*w2v[nt];
        sr1 += fmaxf(h4[1]+b1v[nt],0.f)*w2v[nt];
        sr2 += fmaxf(h4[2]+b1v[nt],0.f)*w2v[nt];
        sr3 += fmaxf(h4[3]+b1v[nt],0.f)*w2v[nt];
      }
      #pragma unroll
      for(int mask=1; mask<16; mask<<=1){
        sr0 += __shfl_xor(sr0, mask, 64);
        sr1 += __shfl_xor(sr1, mask, 64);
        sr2 += __shfl_xor(sr2, mask, 64);
        sr3 += __shfl_xor(sr3, mask, 64);
      }
      if(l15 < 4){
        float outv = (l15==0)?sr0:(l15==1)?sr1:(l15==2)?sr2:sr3;
        int mt = (u==0)?mt0:mt1;
        scores[(size_t)mt*16 + q*4 + l15] = outv;
      }
    }
  }
}

// ---- masked softmax over S per batch row --------------------------------
__global__ __launch_bounds__(256) void softmax_kernel(
    const float* __restrict__ scores, const int* __restrict__ lengths,
    float* __restrict__ att){
  const int b = blockIdx.x;
  const int s = threadIdx.x;
  const int lane = s & 63, wv = s >> 6;
  __shared__ float red[4];
  __shared__ float red2[4];
  float sc = -1e9f;
  if(s < S_LEN){
    float v = scores[(size_t)b*S_LEN + s];
    sc = (s < lengths[b]) ? v : -1e9f;
  }
  float mx = (s < S_LEN) ? sc : -INFINITY;
  #pragma unroll
  for(int mask=1; mask<64; mask<<=1) mx = fmaxf(mx, __shfl_xor(mx, mask, 64));
  if(lane==0) red[wv] = mx;
  __syncthreads();
  mx = fmaxf(fmaxf(red[0],red[1]), fmaxf(red[2],red[3]));
  float e = (s < S_LEN) ? expf(sc - mx) : 0.f;
  float sum = e;
  #pragma unroll
  for(int mask=1; mask<64; mask<<=1) sum += __shfl_xor(sum, mask, 64);
  if(lane==0) red2[wv] = sum;
  __syncthreads();
  sum = red2[0]+red2[1]+red2[2]+red2[3];
  if(s < S_LEN) att[(size_t)b*S_LEN + s] = e / sum;
}

// ---- GRU scan: 64 blocks x 16 batch rows x 1024 threads (16 waves) ------
// A 1024-thread block REQUIRES 16 co-resident waves/CU -> VGPR cap 128,
// which the compiler always honors (R2-R4: every attribute attempt at a
// 256-reg cap for 512-thread blocks was ignored and spilled ~500 MB/launch).
// Resident h-weights now cost 96 VGPRs/thread (wfr 64 + wfn 32), fitting
// under 128 with accumulators (8) and temps.
// Per wave: GEMM1 2 n-tiles, GEMM2 1 n-tile, chunk GEMM 3 passes.
__global__ __launch_bounds__(1024) void scan_kernel(
    const float* __restrict__ hs, const float* __restrict__ att,
    const short* __restrict__ wx, const short* __restrict__ wrzh,
    const short* __restrict__ wnh,
    const float* __restrict__ br, const float* __restrict__ bz,
    const float* __restrict__ bn, float* __restrict__ out){
  // LDS layout (bytes):
  //   [0,99328)         XP    fp16 [4][16][776] x-projections (+bias), pad 768->776
  //   [99328,115968)    hO    f32  [16][260]    master h, pad 256->260
  //   [115968,149760)   union: xstage bf16 [64][264] (chunk GEMM A)
  //                         | comb0 bf16 [16][264] (h)       @ +0
  //                         | comb1 bf16 [16][264] (r*h)     @ +8448
  //                         | zS    fp16 [16][264]           @ +16896
  //   [149760,150016)   attc  f32 [4][16]
  __shared__ __align__(16) char smem[150016];
  _Float16* XP    = (_Float16*)smem;
  float*    hO    = (float*)(smem + 99328);
  short*    xst   = (short*)(smem + 115968);
  short*    comb0 = (short*)(smem + 115968);
  short*    comb1 = (short*)(smem + 115968 + 8448);
  _Float16* zS    = (_Float16*)(smem + 115968 + 16896);
  float*    attc  = (float*)(smem + 149760);

  const int tid = threadIdx.x;
  const int lane = tid & 63;
  const int wv  = tid >> 6;         // 0..15
  const int l15 = lane & 15;
  const int q   = lane >> 4;
  const int b0  = blockIdx.x * 16;

  // register-resident h-part weight fragments (96 VGPRs)
  s16x8 wfr[16], wfn[8];
  #pragma unroll
  for(int kt=0;kt<8;kt++)
    #pragma unroll
    for(int i=0;i<2;i++)
      wfr[kt*2+i] = *(const s16x8*)(wrzh + (size_t)((wv*2+i)*16+l15)*256 + kt*32 + q*8);
  #pragma unroll
  for(int kt=0;kt<8;kt++)
    wfn[kt] = *(const s16x8*)(wnh + (size_t)(wv*16+l15)*256 + kt*32 + q*8);
  float biasc[3];
  #pragma unroll
  for(int p=0;p<3;p++){
    int o=(wv*3+p)*16+l15;
    biasc[p] = (o<256)? br[o] : (o<512)? bz[o-256] : bn[o-512];
  }
  for(int i=tid;i<16*260;i+=1024) hO[i]=0.f;

  for(int c=0;c<50;c++){
    const int t0=c*4;
    __syncthreads();                         // B1: prior step done; union region free
    // stage x (4 steps x 16 rows) as bf16 into xstage
    #pragma unroll
    for(int jj=0;jj<2;jj++){
      int idx = tid + jj*1024;               // 0..2047
      int r = idx>>5, k=(idx&31)*8;          // r = tl*16+bl
      int bl=r&15, tl=r>>4;
      const float* src = hs + ((size_t)(b0+bl)*S_LEN + (t0+tl))*H_DIM + k;
      float4 v0=*(const float4*)src, v1=*(const float4*)(src+4);
      s16x8 xv;
      xv[0]=f2bf(v0.x); xv[1]=f2bf(v0.y); xv[2]=f2bf(v0.z); xv[3]=f2bf(v0.w);
      xv[4]=f2bf(v1.x); xv[5]=f2bf(v1.y); xv[6]=f2bf(v1.z); xv[7]=f2bf(v1.w);
      *(s16x8*)(xst + r*264 + k) = xv;
    }
    if(tid<64) attc[tid] = att[(size_t)(b0+(tid&15))*S_LEN + t0 + (tid>>4)];
    __syncthreads();                         // B2: xstage + attc ready
    // chunk GEMM: XP[tl][row][0:768] = x @ Wx^T + bias
    // 3 passes x 1 n-tile: 16 live acc regs
    #pragma unroll
    for(int p=0;p<3;p++){
      f32x4 xacc[4];
      #pragma unroll
      for(int tl=0;tl<4;tl++) xacc[tl]=(f32x4){0.f,0.f,0.f,0.f};
      #pragma unroll
      for(int kt=0;kt<8;kt++){
        s16x8 bf0 = *(const s16x8*)(wx + (size_t)((wv*3+p)*16+l15)*256 + kt*32+q*8);
        #pragma unroll
        for(int tl=0;tl<4;tl++){
          s16x8 a = *(const s16x8*)(xst + (tl*16+l15)*264 + kt*32 + q*8);
          xacc[tl]=__builtin_amdgcn_mfma_f32_16x16x32_bf16(a,bf0,xacc[tl],0,0,0);
        }
      }
      int col=(wv*3+p)*16+l15;
      float bias=biasc[p];
      #pragma unroll
      for(int tl=0;tl<4;tl++)
        #pragma unroll
        for(int reg=0;reg<4;reg++)
          XP[(size_t)(tl*16 + q*4+reg)*776 + col] = (_Float16)(xacc[tl][reg] + bias);
    }
    __syncthreads();                         // B3: XP ready; xstage reads done
    // rebuild comb0 (=h bf16) from hO over the aliased region
    #pragma unroll
    for(int jj=0;jj<4;jj++){
      int idx=tid+jj*1024;                   // 0..4095
      int rr=idx>>8, cc=idx&255;
      comb0[rr*264+cc]=f2bf(hO[rr*260+cc]);
    }
    __syncthreads();                         // B4: comb0 ready
    // ---- 4 recurrence steps, 2 barriers each (comb double-buffered) ----
    for(int tl=0;tl<4;tl++){
      // GEMM1: h(16x256) @ [Wr_h;Wz_h]^T ; reads comb0; 2 n-tiles/wave
      f32x4 acc[2];
      #pragma unroll
      for(int i=0;i<2;i++) acc[i]=(f32x4){0.f,0.f,0.f,0.f};
      #pragma unroll
      for(int kt=0;kt<8;kt++){
        s16x8 a = *(const s16x8*)(comb0 + l15*264 + kt*32+q*8);
        #pragma unroll
        for(int i=0;i<2;i++)
          acc[i]=__builtin_amdgcn_mfma_f32_16x16x32_bf16(a,wfr[kt*2+i],acc[i],0,0,0);
      }
      // epi1: r -> comb1 (waves 0-7), z -> zS (waves 8-15); no comb0 writes
      #pragma unroll
      for(int i=0;i<2;i++){
        int o=(wv*2+i)*16+l15;               // wave-uniform branch below
        #pragma unroll
        for(int reg=0;reg<4;reg++){
          int row=q*4+reg;
          float pre = acc[i][reg] + (float)XP[(size_t)(tl*16+row)*776 + o];
          float g = sigm(pre);
          if(o<256){
            comb1[row*264+o] = f2bf(g*hO[row*260+o]);          // r*h
          } else {
            zS[row*264+(o-256)] = (_Float16)(g*attc[tl*16+row]); // z = sig*att
          }
        }
      }
      __syncthreads();                       // C: comb1/zS ready, comb0 reads done
      // GEMM2: [r*h](16x256) @ Wn_h^T ; reads comb1; 1 n-tile/wave
      f32x4 acc2 = (f32x4){0.f,0.f,0.f,0.f};
      #pragma unroll
      for(int kt=0;kt<8;kt++){
        s16x8 a = *(const s16x8*)(comb1 + l15*264 + kt*32+q*8);
        acc2=__builtin_amdgcn_mfma_f32_16x16x32_bf16(a,wfn[kt],acc2,0,0,0);
      }
      // epi2: h update -> hO + comb0 (next step's GEMM1 input)
      {
        int cc=wv*16+l15;
        #pragma unroll
        for(int reg=0;reg<4;reg++){
          int row=q*4+reg;
          float nv = tanh_f(acc2[reg] + (float)XP[(size_t)(tl*16+row)*776 + 512+cc]);
          float z  = (float)zS[row*264+cc];
          float hp = hO[row*260+cc];
          float hn = fmaf(z, nv-hp, hp);
          hO[row*260+cc]=hn;
          comb0[row*264+cc]=f2bf(hn);
        }
      }
      __syncthreads();                       // A: comb0(next h) ready, comb1 reads done
    }
  }
  float4 o0;
  const int orow = tid>>6, ocol = (tid&63)*4;
  o0.x=hO[orow*260+ocol+0]; o0.y=hO[orow*260+ocol+1];
  o0.z=hO[orow*260+ocol+2]; o0.w=hO[orow*260+ocol+3];
  float* op = out + (size_t)(b0+orow)*H_DIM + ocol;
  *(float4*)op = o0;
}

extern "C" void kernel_launch(void* const* d_in, const int* in_sizes, int n_in,
                              void* d_out, int out_size, void* d_ws, size_t ws_size,
                              hipStream_t stream) {
  const float* hs  = (const float*)d_in[0];
  const float* tgt = (const float*)d_in[1];
  const int*   len = (const int*)d_in[2];
  const float* W1  = (const float*)d_in[3];
  const float* b1  = (const float*)d_in[4];
  const float* W2  = (const float*)d_in[5];
  const float* Wr  = (const float*)d_in[6];
  const float* br  = (const float*)d_in[7];
  const float* Wz  = (const float*)d_in[8];
  const float* bz  = (const float*)d_in[9];
  const float* Wn  = (const float*)d_in[10];
  const float* bn  = (const float*)d_in[11];
  float* out = (float*)d_out;
  // ws: wx[768*256] | wrzh[512*256] | wnh[256*256] | w1b[128*512] | scores | att
  short* wx   = (short*)d_ws;
  short* wrzh = wx + 196608;
  short* wnh  = wrzh + 131072;
  short* w1b  = wnh + 65536;
  float* scores = (float*)(w1b + 65536);
  float* att    = scores + (size_t)B_SZ*S_LEN;
  prep_kernel<<<1792, 256, 0, stream>>>(Wr, Wz, Wn, W1, wx, wrzh, wnh, w1b);
  scores_kernel<<<800, 256, 0, stream>>>(hs, tgt, w1b, b1, W2, scores);
  softmax_kernel<<<1024, 256, 0, stream>>>(scores, len, att);
  scan_kernel<<<64, 1024, 0, stream>>>(hs, att, wx, wrzh, wnh, br, bz, bn, out);
}